// Round 4
// baseline (278.355 us; speedup 1.0000x reference)
//
#include <hip/hip_runtime.h>
#include <hip/hip_bf16.h>

typedef float  f32x4  __attribute__((ext_vector_type(4)));
typedef unsigned long long u64;

#define N_ROWS 65536
#define N_F    512
#define N_CLU  1024

template <bool HI>
static __device__ __forceinline__ unsigned pk8(float a, float b, unsigned old) {
  return (unsigned)__builtin_amdgcn_cvt_pk_fp8_f32(a, b, (int)old, HI);
}

// ---- kernel 1: L2-normalize m rows, store fp8-e4m3 row-major [1024][512] ----
__global__ __launch_bounds__(256) void knorm_m(const float* __restrict__ m,
                                               uint2* __restrict__ mn) {
  const int wave = threadIdx.x >> 6, lane = threadIdx.x & 63;
  const int row = blockIdx.x * 4 + wave;
  const float* p = m + (size_t)row * N_F + lane * 8;
  float4 a = ((const float4*)p)[0];
  float4 b = ((const float4*)p)[1];
  float ss = a.x*a.x + a.y*a.y + a.z*a.z + a.w*a.w
           + b.x*b.x + b.y*b.y + b.z*b.z + b.w*b.w;
#pragma unroll
  for (int off = 1; off < 64; off <<= 1) ss += __shfl_xor(ss, off);
  const float inv = 1.0f / fmaxf(sqrtf(ss), 1e-12f);
  unsigned lo = pk8<false>(a.x*inv, a.y*inv, 0u);
  lo = pk8<true>(a.z*inv, a.w*inv, lo);
  unsigned hi = pk8<false>(b.x*inv, b.y*inv, 0u);
  hi = pk8<true>(b.z*inv, b.w*inv, hi);
  mn[(size_t)row * 64 + lane] = make_uint2(lo, hi);
}

// ---- kernel 2: fused normalize(x) @ mn^T (fp8 MFMA) -> entropy partials ----
// No LDS, no barriers: mn (512 KB fp8) is L2-resident; each wave streams its
// A-fragments directly from global with a 1-tile register double-buffer.
// Waves fully independent -> MFMA/VMEM/VALU overlap via TLP.
__global__ __launch_bounds__(256, 2) void kmain(const float* __restrict__ x,
                                                const u64* __restrict__ mn8,
                                                float* __restrict__ acc_out) {
  const int tid = threadIdx.x, wave = tid >> 6, lane = tid & 63;
  const int r16 = lane & 15, g = lane >> 4;

  long xb0[16], xb1[16];
  float L0 = 0.f, S0 = 0.f, L1 = 0.f, S1 = 0.f;

  // ---- x prologue, two-pass: pass 1 = sum of squares ----
  const int row0 = blockIdx.x * 128 + wave * 32;
  const float* px0 = x + (size_t)(row0 + r16) * N_F + g * 8;
  const float* px1 = x + (size_t)(row0 + 16 + r16) * N_F + g * 8;
  float ss0 = 0.f, ss1 = 0.f;
#pragma unroll
  for (int i = 0; i < 16; ++i) {
    float4 a = *(const float4*)(px0 + i * 32);
    float4 b = *(const float4*)(px0 + i * 32 + 4);
    ss0 += a.x*a.x + a.y*a.y + a.z*a.z + a.w*a.w
         + b.x*b.x + b.y*b.y + b.z*b.z + b.w*b.w;
    float4 c = *(const float4*)(px1 + i * 32);
    float4 d = *(const float4*)(px1 + i * 32 + 4);
    ss1 += c.x*c.x + c.y*c.y + c.z*c.z + c.w*c.w
         + d.x*d.x + d.y*d.y + d.z*d.z + d.w*d.w;
  }
  ss0 += __shfl_xor(ss0, 16); ss0 += __shfl_xor(ss0, 32);
  ss1 += __shfl_xor(ss1, 16); ss1 += __shfl_xor(ss1, 32);
  const float inv0 = 1.0f / fmaxf(sqrtf(ss0), 1e-12f);
  const float inv1 = 1.0f / fmaxf(sqrtf(ss1), 1e-12f);

  // pass 2: reload (L2-hot) and pack normalized fp8 B-fragments
#pragma unroll
  for (int i = 0; i < 16; ++i) {
    float4 a = *(const float4*)(px0 + i * 32);
    float4 b = *(const float4*)(px0 + i * 32 + 4);
    unsigned lo = pk8<false>(a.x*inv0, a.y*inv0, 0u);
    lo = pk8<true>(a.z*inv0, a.w*inv0, lo);
    unsigned hi = pk8<false>(b.x*inv0, b.y*inv0, 0u);
    hi = pk8<true>(b.z*inv0, b.w*inv0, hi);
    xb0[i] = (long)(((u64)hi << 32) | lo);
    float4 c = *(const float4*)(px1 + i * 32);
    float4 d = *(const float4*)(px1 + i * 32 + 4);
    unsigned lo1 = pk8<false>(c.x*inv1, c.y*inv1, 0u);
    lo1 = pk8<true>(c.z*inv1, c.w*inv1, lo1);
    unsigned hi1 = pk8<false>(d.x*inv1, d.y*inv1, 0u);
    hi1 = pk8<true>(d.z*inv1, d.w*inv1, hi1);
    xb1[i] = (long)(((u64)hi1 << 32) | lo1);
  }

  // ---- mn fragment addressing: cluster row c -> 64 u64; lane reads 8 B ----
  // u64 index = (t*32 + r16 (+16))*64 + i*4 + g
  const u64* pw = mn8 + (size_t)r16 * 64 + g;

  long fA[32], fB[32];

  // prefetch tile 0
#pragma unroll
  for (int i = 0; i < 16; ++i) {
    fA[i]      = (long)pw[i * 4];
    fA[16 + i] = (long)pw[1024 + i * 4];
  }

  // one step: fetch tile tn into fn while MFMA-ing fc, then entropy partials
  auto step = [&](const long* fc, long* fn, int tn) {
    const u64* p = pw + (size_t)tn * 2048;
    f32x4 a00 = {0.f,0.f,0.f,0.f}, a01 = {0.f,0.f,0.f,0.f};
    f32x4 a10 = {0.f,0.f,0.f,0.f}, a11 = {0.f,0.f,0.f,0.f};
#pragma unroll
    for (int i = 0; i < 16; ++i) {
      fn[i]      = (long)p[i * 4];
      fn[16 + i] = (long)p[1024 + i * 4];
      a00 = __builtin_amdgcn_mfma_f32_16x16x32_fp8_fp8(fc[i], xb0[i], a00, 0, 0, 0);
      a01 = __builtin_amdgcn_mfma_f32_16x16x32_fp8_fp8(fc[i], xb1[i], a01, 0, 0, 0);
      a10 = __builtin_amdgcn_mfma_f32_16x16x32_fp8_fp8(fc[16 + i], xb0[i], a10, 0, 0, 0);
      a11 = __builtin_amdgcn_mfma_f32_16x16x32_fp8_fp8(fc[16 + i], xb1[i], a11, 0, 0, 0);
    }
#pragma unroll
    for (int r = 0; r < 4; ++r) {
      { float y = a00[r]; float e = __expf(y); L0 += e; S0 = fmaf(e, y, S0); }
      { float y = a10[r]; float e = __expf(y); L0 += e; S0 = fmaf(e, y, S0); }
      { float y = a01[r]; float e = __expf(y); L1 += e; S1 = fmaf(e, y, S1); }
      { float y = a11[r]; float e = __expf(y); L1 += e; S1 = fmaf(e, y, S1); }
    }
  };

#pragma unroll 1
  for (int t = 0; t < 32; t += 2) {
    step(fA, fB, t + 1);                       // t+1 <= 31 always
    step(fB, fA, (t + 2 < 32) ? t + 2 : 31);   // last prefetch is a harmless re-read
  }

  // ---- finish: combine 4 lane-groups (disjoint cluster subsets per row) ----
  float h = 0.f;
  {
    float L = L0; L += __shfl_xor(L, 16); L += __shfl_xor(L, 32);
    float S = S0; S += __shfl_xor(S, 16); S += __shfl_xor(S, 32);
    h += __logf(L) - S / L;
  }
  {
    float L = L1; L += __shfl_xor(L, 16); L += __shfl_xor(L, 32);
    float S = S1; S += __shfl_xor(S, 16); S += __shfl_xor(S, 32);
    h += __logf(L) - S / L;
  }
  h *= 0.25f;   // each row replicated across 4 lanes
#pragma unroll
  for (int off = 1; off < 64; off <<= 1) h += __shfl_xor(h, off);
  if (lane == 0) atomicAdd(acc_out, h);
}

// ---- kernel 3: finalize ----
__global__ void kfin(const float* __restrict__ acc, float* __restrict__ out) {
  const float mean = acc[0] * (1.0f / (float)N_ROWS);
  out[0] = mean;   // total
  out[1] = mean;   // intra
  out[2] = 0.0f;   // inter
}

extern "C" void kernel_launch(void* const* d_in, const int* in_sizes, int n_in,
                              void* d_out, int out_size, void* d_ws, size_t ws_size,
                              hipStream_t stream) {
  const float* x = (const float*)d_in[0];
  const float* m = (const float*)d_in[1];
  float* acc = (float*)d_ws;
  uint2* mn = (uint2*)((char*)d_ws + 64);

  (void)hipMemsetAsync(d_ws, 0, 64, stream);
  knorm_m<<<256, 256, 0, stream>>>(m, mn);
  kmain<<<512, 256, 0, stream>>>(x, (const u64*)mn, acc);
  kfin<<<1, 1, 0, stream>>>(acc, (float*)d_out);
}

// Round 5
// 191.769 us; speedup vs baseline: 1.4515x; 1.4515x over previous
//
#include <hip/hip_runtime.h>
#include <hip/hip_bf16.h>

typedef float  f32x4  __attribute__((ext_vector_type(4)));
typedef unsigned long long u64;

#define N_ROWS 65536
#define N_F    512
#define N_CLU  1024

template <bool HI>
static __device__ __forceinline__ unsigned pk8(float a, float b, unsigned old) {
  return (unsigned)__builtin_amdgcn_cvt_pk_fp8_f32(a, b, (int)old, HI);
}

// ---- kernel 1: L2-normalize m rows -> fp8 e4m3, FRAGMENT-MAJOR layout ----
// mnf u64 index = ((t*2 + rb)*16 + i)*64 + (r16 | g<<4)
//   t = cluster tile (32 rows), rb = 16-row block, i = K-chunk (32B),
//   frag-lane holds row r16, k-bytes [i*32 + g*8, +8)
// => kmain reads a tile as 32 consecutive fully-coalesced 512B loads.
__global__ __launch_bounds__(256) void knorm_m(const float* __restrict__ m,
                                               u64* __restrict__ mnf) {
  const int wave = threadIdx.x >> 6, lane = threadIdx.x & 63;
  const int row = blockIdx.x * 4 + wave;
  const float* p = m + (size_t)row * N_F + lane * 8;
  float4 a = ((const float4*)p)[0];
  float4 b = ((const float4*)p)[1];
  float ss = a.x*a.x + a.y*a.y + a.z*a.z + a.w*a.w
           + b.x*b.x + b.y*b.y + b.z*b.z + b.w*b.w;
#pragma unroll
  for (int off = 1; off < 64; off <<= 1) ss += __shfl_xor(ss, off);
  const float inv = 1.0f / fmaxf(sqrtf(ss), 1e-12f);
  unsigned lo = pk8<false>(a.x*inv, a.y*inv, 0u);
  lo = pk8<true>(a.z*inv, a.w*inv, lo);
  unsigned hi = pk8<false>(b.x*inv, b.y*inv, 0u);
  hi = pk8<true>(b.z*inv, b.w*inv, hi);
  const u64 v = ((u64)hi << 32) | (u64)lo;
  // this lane's 8 k-values = frag (i = lane>>2, g = lane&3) of row `row`
  const int i = lane >> 2, g = lane & 3;
  const int t = row >> 5, rb = (row >> 4) & 1, r16 = row & 15;
  const int lf = r16 | (g << 4);
  mnf[((size_t)(t * 2 + rb) * 16 + i) * 64 + lf] = v;
}

// ---- kernel 2: fused normalize(x) @ mn^T (fp8 MFMA) -> entropy partials ----
// No LDS, no barriers. mn fragments are read coalesced (512B/instr) from the
// L2-resident fragment-major buffer with a 1-tile register double buffer;
// waves fully independent -> MFMA/VMEM/VALU overlap via TLP.
__global__ __launch_bounds__(256, 2) void kmain(const float* __restrict__ x,
                                                const u64* __restrict__ mnf,
                                                float* __restrict__ acc_out) {
  const int tid = threadIdx.x, wave = tid >> 6, lane = tid & 63;
  const int r16 = lane & 15, g = lane >> 4;

  long xb0[16], xb1[16];
  float L0 = 0.f, S0 = 0.f, L1 = 0.f, S1 = 0.f;

  // ---- x prologue, two-pass: pass 1 = sum of squares ----
  const int row0 = blockIdx.x * 128 + wave * 32;
  const float* px0 = x + (size_t)(row0 + r16) * N_F + g * 8;
  const float* px1 = x + (size_t)(row0 + 16 + r16) * N_F + g * 8;
  float ss0 = 0.f, ss1 = 0.f;
#pragma unroll
  for (int i = 0; i < 16; ++i) {
    float4 a = *(const float4*)(px0 + i * 32);
    float4 b = *(const float4*)(px0 + i * 32 + 4);
    ss0 += a.x*a.x + a.y*a.y + a.z*a.z + a.w*a.w
         + b.x*b.x + b.y*b.y + b.z*b.z + b.w*b.w;
    float4 c = *(const float4*)(px1 + i * 32);
    float4 d = *(const float4*)(px1 + i * 32 + 4);
    ss1 += c.x*c.x + c.y*c.y + c.z*c.z + c.w*c.w
         + d.x*d.x + d.y*d.y + d.z*d.z + d.w*d.w;
  }
  ss0 += __shfl_xor(ss0, 16); ss0 += __shfl_xor(ss0, 32);
  ss1 += __shfl_xor(ss1, 16); ss1 += __shfl_xor(ss1, 32);
  const float inv0 = 1.0f / fmaxf(sqrtf(ss0), 1e-12f);
  const float inv1 = 1.0f / fmaxf(sqrtf(ss1), 1e-12f);

  // pass 2: reload (cache-hot) and pack normalized fp8 B-fragments
#pragma unroll
  for (int i = 0; i < 16; ++i) {
    float4 a = *(const float4*)(px0 + i * 32);
    float4 b = *(const float4*)(px0 + i * 32 + 4);
    unsigned lo = pk8<false>(a.x*inv0, a.y*inv0, 0u);
    lo = pk8<true>(a.z*inv0, a.w*inv0, lo);
    unsigned hi = pk8<false>(b.x*inv0, b.y*inv0, 0u);
    hi = pk8<true>(b.z*inv0, b.w*inv0, hi);
    xb0[i] = (long)(((u64)hi << 32) | lo);
    float4 c = *(const float4*)(px1 + i * 32);
    float4 d = *(const float4*)(px1 + i * 32 + 4);
    unsigned lo1 = pk8<false>(c.x*inv1, c.y*inv1, 0u);
    lo1 = pk8<true>(c.z*inv1, c.w*inv1, lo1);
    unsigned hi1 = pk8<false>(d.x*inv1, d.y*inv1, 0u);
    hi1 = pk8<true>(d.z*inv1, d.w*inv1, hi1);
    xb1[i] = (long)(((u64)hi1 << 32) | lo1);
  }

  // ---- mn fragment pointer: tile t frag j (j=0..31) at pw[t*2048 + j*64] ----
  const u64* pw = mnf + lane;

  long fA[32], fB[32];

  // prefetch tile 0 (32 coalesced 512B loads)
#pragma unroll
  for (int j = 0; j < 32; ++j) fA[j] = (long)pw[j * 64];

  // one step: fetch tile tn into fn while MFMA-ing fc, then entropy partials
  auto step = [&](const long* fc, long* fn, int tn) {
    const u64* p = pw + (size_t)tn * 2048;
#pragma unroll
    for (int j = 0; j < 32; ++j) fn[j] = (long)p[j * 64];
    f32x4 a00 = {0.f,0.f,0.f,0.f}, a01 = {0.f,0.f,0.f,0.f};
    f32x4 a10 = {0.f,0.f,0.f,0.f}, a11 = {0.f,0.f,0.f,0.f};
#pragma unroll
    for (int i = 0; i < 16; ++i) {
      a00 = __builtin_amdgcn_mfma_f32_16x16x32_fp8_fp8(fc[i], xb0[i], a00, 0, 0, 0);
      a01 = __builtin_amdgcn_mfma_f32_16x16x32_fp8_fp8(fc[i], xb1[i], a01, 0, 0, 0);
      a10 = __builtin_amdgcn_mfma_f32_16x16x32_fp8_fp8(fc[16 + i], xb0[i], a10, 0, 0, 0);
      a11 = __builtin_amdgcn_mfma_f32_16x16x32_fp8_fp8(fc[16 + i], xb1[i], a11, 0, 0, 0);
    }
#pragma unroll
    for (int r = 0; r < 4; ++r) {
      { float y = a00[r]; float e = __expf(y); L0 += e; S0 = fmaf(e, y, S0); }
      { float y = a10[r]; float e = __expf(y); L0 += e; S0 = fmaf(e, y, S0); }
      { float y = a01[r]; float e = __expf(y); L1 += e; S1 = fmaf(e, y, S1); }
      { float y = a11[r]; float e = __expf(y); L1 += e; S1 = fmaf(e, y, S1); }
    }
  };

#pragma unroll 1
  for (int t = 0; t < 32; t += 2) {
    step(fA, fB, t + 1);                       // t+1 <= 31 always
    step(fB, fA, (t + 2 < 32) ? t + 2 : 31);   // last prefetch = harmless re-read
  }

  // ---- finish: combine 4 lane-groups (disjoint cluster subsets per row) ----
  float h = 0.f;
  {
    float L = L0; L += __shfl_xor(L, 16); L += __shfl_xor(L, 32);
    float S = S0; S += __shfl_xor(S, 16); S += __shfl_xor(S, 32);
    h += __logf(L) - S / L;
  }
  {
    float L = L1; L += __shfl_xor(L, 16); L += __shfl_xor(L, 32);
    float S = S1; S += __shfl_xor(S, 16); S += __shfl_xor(S, 32);
    h += __logf(L) - S / L;
  }
  h *= 0.25f;   // each row replicated across 4 lanes
#pragma unroll
  for (int off = 1; off < 64; off <<= 1) h += __shfl_xor(h, off);
  if (lane == 0) atomicAdd(acc_out, h);
}

// ---- kernel 3: finalize ----
__global__ void kfin(const float* __restrict__ acc, float* __restrict__ out) {
  const float mean = acc[0] * (1.0f / (float)N_ROWS);
  out[0] = mean;   // total
  out[1] = mean;   // intra
  out[2] = 0.0f;   // inter
}

extern "C" void kernel_launch(void* const* d_in, const int* in_sizes, int n_in,
                              void* d_out, int out_size, void* d_ws, size_t ws_size,
                              hipStream_t stream) {
  const float* x = (const float*)d_in[0];
  const float* m = (const float*)d_in[1];
  float* acc = (float*)d_ws;
  u64* mnf = (u64*)((char*)d_ws + 64);

  (void)hipMemsetAsync(d_ws, 0, 64, stream);
  knorm_m<<<256, 256, 0, stream>>>(m, mnf);
  kmain<<<512, 256, 0, stream>>>(x, mnf, acc);
  kfin<<<1, 1, 0, stream>>>(acc, (float*)d_out);
}

// Round 6
// 169.104 us; speedup vs baseline: 1.6461x; 1.1340x over previous
//
#include <hip/hip_runtime.h>
#include <hip/hip_bf16.h>

typedef float  f32x4  __attribute__((ext_vector_type(4)));
typedef unsigned long long u64;

#define N_ROWS 65536
#define N_F    512
#define N_CLU  1024

template <bool HI>
static __device__ __forceinline__ unsigned pk8(float a, float b, unsigned old) {
  return (unsigned)__builtin_amdgcn_cvt_pk_fp8_f32(a, b, (int)old, HI);
}

// ---- kernel 1: L2-normalize m rows -> fp8 e4m3, FRAGMENT-MAJOR layout ----
// mnf u64 index = ((t*2 + rb)*16 + i)*64 + (r16 | g<<4)
//   t = 32-cluster tile, rb = 16-row block, i = 32B K-chunk;
//   frag-lane (r16|g<<4) holds row t*32+rb*16+r16, k-bytes [i*32+g*8, +8)
__global__ __launch_bounds__(256) void knorm_m(const float* __restrict__ m,
                                               u64* __restrict__ mnf) {
  const int wave = threadIdx.x >> 6, lane = threadIdx.x & 63;
  const int row = blockIdx.x * 4 + wave;
  const float* p = m + (size_t)row * N_F + lane * 8;
  float4 a = ((const float4*)p)[0];
  float4 b = ((const float4*)p)[1];
  float ss = a.x*a.x + a.y*a.y + a.z*a.z + a.w*a.w
           + b.x*b.x + b.y*b.y + b.z*b.z + b.w*b.w;
#pragma unroll
  for (int off = 1; off < 64; off <<= 1) ss += __shfl_xor(ss, off);
  const float inv = 1.0f / fmaxf(sqrtf(ss), 1e-12f);
  unsigned lo = pk8<false>(a.x*inv, a.y*inv, 0u);
  lo = pk8<true>(a.z*inv, a.w*inv, lo);
  unsigned hi = pk8<false>(b.x*inv, b.y*inv, 0u);
  hi = pk8<true>(b.z*inv, b.w*inv, hi);
  const u64 v = ((u64)hi << 32) | (u64)lo;
  const int i = lane >> 2, g = lane & 3;
  const int t = row >> 5, rb = (row >> 4) & 1, r16 = row & 15;
  mnf[((size_t)(t * 2 + rb) * 16 + i) * 64 + (r16 | (g << 4))] = v;
}

// ---- kernel 2: fused normalize(x) @ mn^T (fp8 MFMA) -> entropy partials ----
// 512 thr = 8 waves = 4 row-groups x 2 cluster-halves. Wave owns 32 x-rows
// (registers) x 16 clusters per tile. Fragment-major LDS (conflict-free b64
// reads/writes), reg-staged 2-ahead prefetch, lgkm-only barrier per tile.
__global__ __launch_bounds__(512, 4) void kmain(const float* __restrict__ x,
                                                const u64* __restrict__ mnf,
                                                float* __restrict__ acc_out) {
  __shared__ __align__(16) u64 mbuf[2][32 * 64];   // 2 x 16 KiB
  const int tid = threadIdx.x, wave = tid >> 6, lane = tid & 63;
  const int rg = wave >> 1, ch = wave & 1;
  const int r16 = lane & 15, g = lane >> 4;

  long xb0[16], xb1[16];
  float L0 = 0.f, S0 = 0.f, L1 = 0.f, S1 = 0.f;

  // staging: thread covers mnf[t*2048 + q*512 + tid], q=0..3 (coalesced)
  auto loadset = [&](u64* s, int t) {
    const u64* p = mnf + (size_t)t * 2048 + tid;
#pragma unroll
    for (int q = 0; q < 4; ++q) s[q] = p[q * 512];
  };
  auto writeset = [&](const u64* s, int b) {
    u64* d = &mbuf[b][tid];
#pragma unroll
    for (int q = 0; q < 4; ++q) d[q * 512] = s[q];
  };

  u64 sA[4], sB[4];
  loadset(sA, 0);    // issue early; x prologue hides latency
  loadset(sB, 1);

  // ---- x prologue, two-pass: pass 1 = sum of squares ----
  const int row0 = blockIdx.x * 128 + rg * 32;
  const float* px0 = x + (size_t)(row0 + r16) * N_F + g * 8;
  const float* px1 = x + (size_t)(row0 + 16 + r16) * N_F + g * 8;
  float ss0 = 0.f, ss1 = 0.f;
#pragma unroll
  for (int i = 0; i < 16; ++i) {
    float4 a = *(const float4*)(px0 + i * 32);
    float4 b = *(const float4*)(px0 + i * 32 + 4);
    ss0 += a.x*a.x + a.y*a.y + a.z*a.z + a.w*a.w
         + b.x*b.x + b.y*b.y + b.z*b.z + b.w*b.w;
    float4 c = *(const float4*)(px1 + i * 32);
    float4 d = *(const float4*)(px1 + i * 32 + 4);
    ss1 += c.x*c.x + c.y*c.y + c.z*c.z + c.w*c.w
         + d.x*d.x + d.y*d.y + d.z*d.z + d.w*d.w;
  }
  ss0 += __shfl_xor(ss0, 16); ss0 += __shfl_xor(ss0, 32);
  ss1 += __shfl_xor(ss1, 16); ss1 += __shfl_xor(ss1, 32);
  const float inv0 = 1.0f / fmaxf(sqrtf(ss0), 1e-12f);
  const float inv1 = 1.0f / fmaxf(sqrtf(ss1), 1e-12f);

  // pass 2: reload (cache-hot) and pack normalized fp8 B-fragments
#pragma unroll
  for (int i = 0; i < 16; ++i) {
    float4 a = *(const float4*)(px0 + i * 32);
    float4 b = *(const float4*)(px0 + i * 32 + 4);
    unsigned lo = pk8<false>(a.x*inv0, a.y*inv0, 0u);
    lo = pk8<true>(a.z*inv0, a.w*inv0, lo);
    unsigned hi = pk8<false>(b.x*inv0, b.y*inv0, 0u);
    hi = pk8<true>(b.z*inv0, b.w*inv0, hi);
    xb0[i] = (long)(((u64)hi << 32) | lo);
    float4 c = *(const float4*)(px1 + i * 32);
    float4 d = *(const float4*)(px1 + i * 32 + 4);
    unsigned lo1 = pk8<false>(c.x*inv1, c.y*inv1, 0u);
    lo1 = pk8<true>(c.z*inv1, c.w*inv1, lo1);
    unsigned hi1 = pk8<false>(d.x*inv1, d.y*inv1, 0u);
    hi1 = pk8<true>(d.z*inv1, d.w*inv1, hi1);
    xb1[i] = (long)(((u64)hi1 << 32) | lo1);
  }

  // per-tile compute: wave reads its cluster-half frags (conflict-free b64)
  auto tile = [&](int b) {
    const u64* mb = &mbuf[b][(size_t)ch * 1024 + lane];
    f32x4 a0 = {0.f,0.f,0.f,0.f}, a1 = {0.f,0.f,0.f,0.f};
#pragma unroll
    for (int i = 0; i < 16; ++i) {
      long af = (long)mb[i * 64];
      a0 = __builtin_amdgcn_mfma_f32_16x16x32_fp8_fp8(af, xb0[i], a0, 0, 0, 0);
      a1 = __builtin_amdgcn_mfma_f32_16x16x32_fp8_fp8(af, xb1[i], a1, 0, 0, 0);
    }
#pragma unroll
    for (int r = 0; r < 4; ++r) {
      { float y = a0[r]; float e = __expf(y); L0 += e; S0 = fmaf(e, y, S0); }
      { float y = a1[r]; float e = __expf(y); L1 += e; S1 = fmaf(e, y, S1); }
    }
  };

  writeset(sA, 0);
  loadset(sA, 2);
  asm volatile("s_waitcnt lgkmcnt(0)" ::: "memory");
  __builtin_amdgcn_s_barrier();

#pragma unroll 1
  for (int t = 0; t < 32; t += 2) {
    // even tile t (buf 0)
    writeset(sB, 1);                    // tile t+1 -> buf1 (t+1 <= 31 always)
    if (t + 3 < 32) loadset(sB, t + 3);
    tile(0);
    asm volatile("s_waitcnt lgkmcnt(0)" ::: "memory");
    __builtin_amdgcn_s_barrier();
    // odd tile t+1 (buf 1)
    if (t + 2 < 32) writeset(sA, 0);    // tile t+2 -> buf0
    if (t + 4 < 32) loadset(sA, t + 4);
    tile(1);
    asm volatile("s_waitcnt lgkmcnt(0)" ::: "memory");
    __builtin_amdgcn_s_barrier();
  }

  // ---- finish ----
  // reduce over the 4 g-groups (disjoint cluster subsets of this half)
  L0 += __shfl_xor(L0, 16); L0 += __shfl_xor(L0, 32);
  S0 += __shfl_xor(S0, 16); S0 += __shfl_xor(S0, 32);
  L1 += __shfl_xor(L1, 16); L1 += __shfl_xor(L1, 32);
  S1 += __shfl_xor(S1, 16); S1 += __shfl_xor(S1, 32);

  // combine the two cluster-halves via LDS scratch (reuse mbuf)
  float* sc = (float*)&mbuf[0][0];   // [128 rows][2 ch][2 (L,S)]
  const int rbase = rg * 32;
  if (lane < 16) {
    const int idx = ((rbase + r16) * 2 + ch) * 2;
    sc[idx] = L0; sc[idx + 1] = S0;
  } else if (lane < 32) {
    const int idx = ((rbase + 16 + (lane & 15)) * 2 + ch) * 2;
    sc[idx] = L1; sc[idx + 1] = S1;
  }
  __syncthreads();
  if (tid < 128) {
    const float L = sc[tid * 4 + 0] + sc[tid * 4 + 2];
    const float S = sc[tid * 4 + 1] + sc[tid * 4 + 3];
    float h = __logf(L) - S / L;
#pragma unroll
    for (int off = 1; off < 64; off <<= 1) h += __shfl_xor(h, off);
    if (lane == 0) atomicAdd(acc_out, h);
  }
}

// ---- kernel 3: finalize ----
__global__ void kfin(const float* __restrict__ acc, float* __restrict__ out) {
  const float mean = acc[0] * (1.0f / (float)N_ROWS);
  out[0] = mean;   // total
  out[1] = mean;   // intra
  out[2] = 0.0f;   // inter
}

extern "C" void kernel_launch(void* const* d_in, const int* in_sizes, int n_in,
                              void* d_out, int out_size, void* d_ws, size_t ws_size,
                              hipStream_t stream) {
  const float* x = (const float*)d_in[0];
  const float* m = (const float*)d_in[1];
  float* acc = (float*)d_ws;
  u64* mnf = (u64*)((char*)d_ws + 64);

  (void)hipMemsetAsync(d_ws, 0, 64, stream);
  knorm_m<<<256, 256, 0, stream>>>(m, mnf);
  kmain<<<512, 512, 0, stream>>>(x, mnf, acc);
  kfin<<<1, 1, 0, stream>>>(acc, (float*)d_out);
}

// Round 7
// 112.638 us; speedup vs baseline: 2.4712x; 1.5013x over previous
//
#include <hip/hip_runtime.h>
#include <hip/hip_bf16.h>

typedef float  f32x4  __attribute__((ext_vector_type(4)));
typedef unsigned long long u64;

#define N_ROWS 65536
#define N_F    512
#define N_CLU  1024

template <bool HI>
static __device__ __forceinline__ unsigned pk8(float a, float b, unsigned old) {
  return (unsigned)__builtin_amdgcn_cvt_pk_fp8_f32(a, b, (int)old, HI);
}

// ---- kernel 1: L2-normalize m rows -> fp8 e4m3, FRAGMENT-MAJOR layout ----
// mnf u64 index = ((t*2 + rb)*16 + i)*64 + (r16 | g<<4)
//   t = 32-cluster tile, rb = 16-row block, i = 32B K-chunk;
//   frag-lane (r16|g<<4) holds row t*32+rb*16+r16, k-bytes [i*32+g*8, +8)
__global__ __launch_bounds__(256) void knorm_m(const float* __restrict__ m,
                                               u64* __restrict__ mnf) {
  const int wave = threadIdx.x >> 6, lane = threadIdx.x & 63;
  const int row = blockIdx.x * 4 + wave;
  const float* p = m + (size_t)row * N_F + lane * 8;
  float4 a = ((const float4*)p)[0];
  float4 b = ((const float4*)p)[1];
  float ss = a.x*a.x + a.y*a.y + a.z*a.z + a.w*a.w
           + b.x*b.x + b.y*b.y + b.z*b.z + b.w*b.w;
#pragma unroll
  for (int off = 1; off < 64; off <<= 1) ss += __shfl_xor(ss, off);
  const float inv = 1.0f / fmaxf(sqrtf(ss), 1e-12f);
  unsigned lo = pk8<false>(a.x*inv, a.y*inv, 0u);
  lo = pk8<true>(a.z*inv, a.w*inv, lo);
  unsigned hi = pk8<false>(b.x*inv, b.y*inv, 0u);
  hi = pk8<true>(b.z*inv, b.w*inv, hi);
  const u64 v = ((u64)hi << 32) | (u64)lo;
  const int i = lane >> 2, g = lane & 3;
  const int t = row >> 5, rb = (row >> 4) & 1, r16 = row & 15;
  mnf[((size_t)(t * 2 + rb) * 16 + i) * 64 + (r16 | (g << 4))] = v;
}

// ---- kernel 2: fused x @ mn^T (fp8 MFMA) -> entropy partials ----
// 512 thr = 8 waves = 4 row-groups x 2 cluster-halves. Wave owns 32 x-rows
// (raw-fp8 registers; logits scaled by 1/||x|| in epilogue) x 16 clusters per
// tile. Fragment-major LDS (conflict-free b64), reg-staged 2-ahead prefetch,
// lgkm-only barrier per tile so prefetch VMEM stays in flight.
__global__ __launch_bounds__(512, 2) void kmain(const float* __restrict__ x,
                                                const u64* __restrict__ mnf,
                                                float* __restrict__ acc_out) {
  __shared__ __align__(16) u64 mbuf[2][32 * 64];   // 2 x 16 KiB
  const int tid = threadIdx.x, wave = tid >> 6, lane = tid & 63;
  const int rg = wave >> 1, ch = wave & 1;
  const int r16 = lane & 15, g = lane >> 4;

  long xb0[16], xb1[16];
  float L0 = 0.f, S0 = 0.f, L1 = 0.f, S1 = 0.f;

  // staging: thread covers mnf[t*2048 + q*512 + tid], q=0..3 (coalesced)
  auto loadset = [&](u64* s, int t) {
    const u64* p = mnf + (size_t)t * 2048 + tid;
#pragma unroll
    for (int q = 0; q < 4; ++q) s[q] = p[q * 512];
  };
  auto writeset = [&](const u64* s, int b) {
    u64* d = &mbuf[b][tid];
#pragma unroll
    for (int q = 0; q < 4; ++q) d[q * 512] = s[q];
  };

  u64 sA[4], sB[4];
  loadset(sA, 0);    // issue early; x prologue hides latency
  loadset(sB, 1);

  // ---- x prologue, single pass: pack RAW fp8 + accumulate sum-of-squares ----
  const int row0 = blockIdx.x * 128 + rg * 32;
  const float* px0 = x + (size_t)(row0 + r16) * N_F + g * 8;
  const float* px1 = x + (size_t)(row0 + 16 + r16) * N_F + g * 8;
  float ss0 = 0.f, ss1 = 0.f;
#pragma unroll
  for (int i = 0; i < 16; ++i) {
    float4 a = *(const float4*)(px0 + i * 32);
    float4 b = *(const float4*)(px0 + i * 32 + 4);
    ss0 += a.x*a.x + a.y*a.y + a.z*a.z + a.w*a.w
         + b.x*b.x + b.y*b.y + b.z*b.z + b.w*b.w;
    unsigned lo = pk8<false>(a.x, a.y, 0u);
    lo = pk8<true>(a.z, a.w, lo);
    unsigned hi = pk8<false>(b.x, b.y, 0u);
    hi = pk8<true>(b.z, b.w, hi);
    xb0[i] = (long)(((u64)hi << 32) | lo);
    float4 c = *(const float4*)(px1 + i * 32);
    float4 d = *(const float4*)(px1 + i * 32 + 4);
    ss1 += c.x*c.x + c.y*c.y + c.z*c.z + c.w*c.w
         + d.x*d.x + d.y*d.y + d.z*d.z + d.w*d.w;
    unsigned lo1 = pk8<false>(c.x, c.y, 0u);
    lo1 = pk8<true>(c.z, c.w, lo1);
    unsigned hi1 = pk8<false>(d.x, d.y, 0u);
    hi1 = pk8<true>(d.z, d.w, hi1);
    xb1[i] = (long)(((u64)hi1 << 32) | lo1);
  }
  ss0 += __shfl_xor(ss0, 16); ss0 += __shfl_xor(ss0, 32);
  ss1 += __shfl_xor(ss1, 16); ss1 += __shfl_xor(ss1, 32);
  const float inv0 = 1.0f / fmaxf(sqrtf(ss0), 1e-12f);   // per-lane = x-row r16
  const float inv1 = 1.0f / fmaxf(sqrtf(ss1), 1e-12f);

  // per-tile compute: wave reads its cluster-half frags (conflict-free b64);
  // logits y = inv * (x_raw . m_hat)
  auto tile = [&](int b) {
    const u64* mb = &mbuf[b][(size_t)ch * 1024 + lane];
    f32x4 a0 = {0.f,0.f,0.f,0.f}, a1 = {0.f,0.f,0.f,0.f};
#pragma unroll
    for (int i = 0; i < 16; ++i) {
      long af = (long)mb[i * 64];
      a0 = __builtin_amdgcn_mfma_f32_16x16x32_fp8_fp8(af, xb0[i], a0, 0, 0, 0);
      a1 = __builtin_amdgcn_mfma_f32_16x16x32_fp8_fp8(af, xb1[i], a1, 0, 0, 0);
    }
#pragma unroll
    for (int r = 0; r < 4; ++r) {
      { float y = a0[r] * inv0; float e = __expf(y); L0 += e; S0 = fmaf(e, y, S0); }
      { float y = a1[r] * inv1; float e = __expf(y); L1 += e; S1 = fmaf(e, y, S1); }
    }
  };

  writeset(sA, 0);
  loadset(sA, 2);
  asm volatile("s_waitcnt lgkmcnt(0)" ::: "memory");
  __builtin_amdgcn_s_barrier();

#pragma unroll 1
  for (int t = 0; t < 32; t += 2) {
    // even tile t (buf 0)
    writeset(sB, 1);                    // tile t+1 -> buf1 (t+1 <= 31 always)
    if (t + 3 < 32) loadset(sB, t + 3);
    tile(0);
    asm volatile("s_waitcnt lgkmcnt(0)" ::: "memory");
    __builtin_amdgcn_s_barrier();
    // odd tile t+1 (buf 1)
    if (t + 2 < 32) writeset(sA, 0);    // tile t+2 -> buf0
    if (t + 4 < 32) loadset(sA, t + 4);
    tile(1);
    asm volatile("s_waitcnt lgkmcnt(0)" ::: "memory");
    __builtin_amdgcn_s_barrier();
  }

  // ---- finish ----
  // reduce over the 4 g-groups (disjoint cluster subsets of this half)
  L0 += __shfl_xor(L0, 16); L0 += __shfl_xor(L0, 32);
  S0 += __shfl_xor(S0, 16); S0 += __shfl_xor(S0, 32);
  L1 += __shfl_xor(L1, 16); L1 += __shfl_xor(L1, 32);
  S1 += __shfl_xor(S1, 16); S1 += __shfl_xor(S1, 32);

  // combine the two cluster-halves via LDS scratch (reuse mbuf)
  float* sc = (float*)&mbuf[0][0];   // [128 rows][2 ch][2 (L,S)]
  const int rbase = rg * 32;
  if (lane < 16) {
    const int idx = ((rbase + r16) * 2 + ch) * 2;
    sc[idx] = L0; sc[idx + 1] = S0;
  } else if (lane < 32) {
    const int idx = ((rbase + 16 + (lane & 15)) * 2 + ch) * 2;
    sc[idx] = L1; sc[idx + 1] = S1;
  }
  __syncthreads();
  if (tid < 128) {
    const float L = sc[tid * 4 + 0] + sc[tid * 4 + 2];
    const float S = sc[tid * 4 + 1] + sc[tid * 4 + 3];
    float h = __logf(L) - S / L;
#pragma unroll
    for (int off = 1; off < 64; off <<= 1) h += __shfl_xor(h, off);
    if (lane == 0) atomicAdd(acc_out, h);
  }
}

// ---- kernel 3: finalize ----
__global__ void kfin(const float* __restrict__ acc, float* __restrict__ out) {
  const float mean = acc[0] * (1.0f / (float)N_ROWS);
  out[0] = mean;   // total
  out[1] = mean;   // intra
  out[2] = 0.0f;   // inter
}

extern "C" void kernel_launch(void* const* d_in, const int* in_sizes, int n_in,
                              void* d_out, int out_size, void* d_ws, size_t ws_size,
                              hipStream_t stream) {
  const float* x = (const float*)d_in[0];
  const float* m = (const float*)d_in[1];
  float* acc = (float*)d_ws;
  u64* mnf = (u64*)((char*)d_ws + 64);

  (void)hipMemsetAsync(d_ws, 0, 64, stream);
  knorm_m<<<256, 256, 0, stream>>>(m, mnf);
  kmain<<<512, 512, 0, stream>>>(x, mnf, acc);
  kfin<<<1, 1, 0, stream>>>(acc, (float*)d_out);
}

// Round 8
// 108.584 us; speedup vs baseline: 2.5635x; 1.0373x over previous
//
#include <hip/hip_runtime.h>
#include <hip/hip_bf16.h>

typedef float  f32x4  __attribute__((ext_vector_type(4)));
typedef unsigned long long u64;

#define N_ROWS 65536
#define N_F    512
#define N_CLU  1024

template <bool HI>
static __device__ __forceinline__ unsigned pk8(float a, float b, unsigned old) {
  return (unsigned)__builtin_amdgcn_cvt_pk_fp8_f32(a, b, (int)old, HI);
}

__device__ __forceinline__ void gload_lds16(const void* g, void* l) {
  __builtin_amdgcn_global_load_lds(
      (const __attribute__((address_space(1))) void*)g,
      (__attribute__((address_space(3))) void*)l, 16, 0, 0);
}

// ---- kernel 1: L2-normalize m rows -> fp8 e4m3, FRAGMENT-MAJOR layout ----
// mnf u64 index = ((t*2 + rb)*16 + i)*64 + (r16 | g<<4)
//   => tile t occupies bytes [t*16384, +16384) linearly; frag j (= rb*16+i)
//      of tile t is the 512B span at t*16384 + j*512, lane-consecutive.
__global__ __launch_bounds__(256) void knorm_m(const float* __restrict__ m,
                                               u64* __restrict__ mnf) {
  const int wave = threadIdx.x >> 6, lane = threadIdx.x & 63;
  const int row = blockIdx.x * 4 + wave;
  const float* p = m + (size_t)row * N_F + lane * 8;
  float4 a = ((const float4*)p)[0];
  float4 b = ((const float4*)p)[1];
  float ss = a.x*a.x + a.y*a.y + a.z*a.z + a.w*a.w
           + b.x*b.x + b.y*b.y + b.z*b.z + b.w*b.w;
#pragma unroll
  for (int off = 1; off < 64; off <<= 1) ss += __shfl_xor(ss, off);
  const float inv = 1.0f / fmaxf(sqrtf(ss), 1e-12f);
  unsigned lo = pk8<false>(a.x*inv, a.y*inv, 0u);
  lo = pk8<true>(a.z*inv, a.w*inv, lo);
  unsigned hi = pk8<false>(b.x*inv, b.y*inv, 0u);
  hi = pk8<true>(b.z*inv, b.w*inv, hi);
  const u64 v = ((u64)hi << 32) | (u64)lo;
  const int i = lane >> 2, g = lane & 3;
  const int t = row >> 5, rb = (row >> 4) & 1, r16 = row & 15;
  mnf[((size_t)(t * 2 + rb) * 16 + i) * 64 + (r16 | (g << 4))] = v;
}

// ---- kernel 2: fused x @ mn^T (fp8 MFMA) -> entropy partials ----
// 256 thr = 4 waves; wave owns 16 x-rows (raw-fp8 regs, logits scaled by
// 1/||x||) and covers all 32 clusters of each tile. 2x16KB LDS ring staged
// via global_load_lds (width 16); 1 barrier/tile; 4 independent blocks/CU
// hide each other's drains.
__global__ __launch_bounds__(256, 4) void kmain(const float* __restrict__ x,
                                                const u64* __restrict__ mnf,
                                                float* __restrict__ acc_out) {
  __shared__ __align__(16) char mbuf[2][16384];
  const int tid = threadIdx.x, wave = tid >> 6, lane = tid & 63;
  const int r16 = lane & 15, g = lane >> 4;

  // stage tile t into buffer b: 16KB linear copy, 4x (256 thr x 16B)
  auto stage = [&](int t, int b) {
    const char* gp = (const char*)mnf + (size_t)t * 16384 + wave * 1024 + lane * 16;
    char* lp = &mbuf[b][wave * 1024];   // wave-uniform base; HW adds lane*16
#pragma unroll
    for (int q = 0; q < 4; ++q)
      gload_lds16(gp + q * 4096, lp + q * 4096);
  };

  stage(0, 0);    // issue early; x prologue hides the latency
  stage(1, 1);

  // ---- x prologue, single pass: pack RAW fp8 + accumulate sum-of-squares ----
  long xb[16];
  const int row0 = blockIdx.x * 64 + wave * 16;
  const float* px = x + (size_t)(row0 + r16) * N_F + g * 8;
  float ss = 0.f;
#pragma unroll
  for (int i = 0; i < 16; ++i) {
    float4 a = *(const float4*)(px + i * 32);
    float4 b = *(const float4*)(px + i * 32 + 4);
    ss += a.x*a.x + a.y*a.y + a.z*a.z + a.w*a.w
        + b.x*b.x + b.y*b.y + b.z*b.z + b.w*b.w;
    unsigned lo = pk8<false>(a.x, a.y, 0u);
    lo = pk8<true>(a.z, a.w, lo);
    unsigned hi = pk8<false>(b.x, b.y, 0u);
    hi = pk8<true>(b.z, b.w, hi);
    xb[i] = (long)(((u64)hi << 32) | lo);
  }
  ss += __shfl_xor(ss, 16); ss += __shfl_xor(ss, 32);
  const float inv = 1.0f / fmaxf(sqrtf(ss), 1e-12f);   // per-lane = x-row r16

  float L = 0.f, S = 0.f;

  asm volatile("s_waitcnt vmcnt(4)" ::: "memory");   // tile 0 staged
  __builtin_amdgcn_s_barrier();

#pragma unroll 1
  for (int t = 0; t < 32; ++t) {
    const int b = t & 1;
    if (t + 1 < 32) stage(t + 1, b ^ 1);   // buf^1's readers finished last iter

    const char* mb = &mbuf[b][lane * 8];
    f32x4 a0 = {0.f,0.f,0.f,0.f}, a1 = {0.f,0.f,0.f,0.f};
#pragma unroll
    for (int i = 0; i < 16; ++i) {
      long f0 = *(const long*)(mb + i * 512);          // cluster half 0, frag i
      long f1 = *(const long*)(mb + 8192 + i * 512);   // cluster half 1
      a0 = __builtin_amdgcn_mfma_f32_16x16x32_fp8_fp8(f0, xb[i], a0, 0, 0, 0);
      a1 = __builtin_amdgcn_mfma_f32_16x16x32_fp8_fp8(f1, xb[i], a1, 0, 0, 0);
    }
#pragma unroll
    for (int r = 0; r < 4; ++r) {
      { float y = a0[r] * inv; float e = __expf(y); L += e; S = fmaf(e, y, S); }
      { float y = a1[r] * inv; float e = __expf(y); L += e; S = fmaf(e, y, S); }
    }
    asm volatile("s_waitcnt vmcnt(0)" ::: "memory");   // t+1 staged (issued a full phase ago)
    __builtin_amdgcn_s_barrier();
  }

  // ---- finish: reduce the 4 g-groups (disjoint cluster subsets per row) ----
  L += __shfl_xor(L, 16); L += __shfl_xor(L, 32);
  S += __shfl_xor(S, 16); S += __shfl_xor(S, 32);
  // each row's (L,S) now replicated on 4 lanes -> weight 1/4, butterfly-sum
  float h = 0.25f * (__logf(L) - S / L);
#pragma unroll
  for (int off = 1; off < 64; off <<= 1) h += __shfl_xor(h, off);
  if (lane == 0) atomicAdd(acc_out, h);
}

// ---- kernel 3: finalize ----
__global__ void kfin(const float* __restrict__ acc, float* __restrict__ out) {
  const float mean = acc[0] * (1.0f / (float)N_ROWS);
  out[0] = mean;   // total
  out[1] = mean;   // intra
  out[2] = 0.0f;   // inter
}

extern "C" void kernel_launch(void* const* d_in, const int* in_sizes, int n_in,
                              void* d_out, int out_size, void* d_ws, size_t ws_size,
                              hipStream_t stream) {
  const float* x = (const float*)d_in[0];
  const float* m = (const float*)d_in[1];
  float* acc = (float*)d_ws;
  u64* mnf = (u64*)((char*)d_ws + 64);

  (void)hipMemsetAsync(d_ws, 0, 64, stream);
  knorm_m<<<256, 256, 0, stream>>>(m, mnf);
  kmain<<<1024, 256, 0, stream>>>(x, mnf, acc);
  kfin<<<1, 1, 0, stream>>>(acc, (float*)d_out);
}

// Round 9
// 108.300 us; speedup vs baseline: 2.5702x; 1.0026x over previous
//
#include <hip/hip_runtime.h>
#include <hip/hip_bf16.h>

typedef float  f32x4  __attribute__((ext_vector_type(4)));
typedef unsigned long long u64;

#define N_ROWS 65536
#define N_F    512
#define N_CLU  1024

template <bool HI>
static __device__ __forceinline__ unsigned pk8(float a, float b, unsigned old) {
  return (unsigned)__builtin_amdgcn_cvt_pk_fp8_f32(a, b, (int)old, HI);
}

__device__ __forceinline__ void gload_lds16(const void* g, void* l) {
  __builtin_amdgcn_global_load_lds(
      (const __attribute__((address_space(1))) void*)g,
      (__attribute__((address_space(3))) void*)l, 16, 0, 0);
}

// ---- kernel 1: L2-normalize m rows -> fp8 e4m3, FRAGMENT-MAJOR layout ----
// mnf u64 index = ((t*2 + rb)*16 + i)*64 + (r16 | g<<4)
//   => tile t occupies bytes [t*16384, +16384) linearly; frag j (= rb*16+i)
//      of tile t is the 512B span at t*16384 + j*512, lane-consecutive.
__global__ __launch_bounds__(256) void knorm_m(const float* __restrict__ m,
                                               u64* __restrict__ mnf) {
  const int wave = threadIdx.x >> 6, lane = threadIdx.x & 63;
  const int row = blockIdx.x * 4 + wave;
  const float* p = m + (size_t)row * N_F + lane * 8;
  float4 a = ((const float4*)p)[0];
  float4 b = ((const float4*)p)[1];
  float ss = a.x*a.x + a.y*a.y + a.z*a.z + a.w*a.w
           + b.x*b.x + b.y*b.y + b.z*b.z + b.w*b.w;
#pragma unroll
  for (int off = 1; off < 64; off <<= 1) ss += __shfl_xor(ss, off);
  const float inv = 1.0f / fmaxf(sqrtf(ss), 1e-12f);
  unsigned lo = pk8<false>(a.x*inv, a.y*inv, 0u);
  lo = pk8<true>(a.z*inv, a.w*inv, lo);
  unsigned hi = pk8<false>(b.x*inv, b.y*inv, 0u);
  hi = pk8<true>(b.z*inv, b.w*inv, hi);
  const u64 v = ((u64)hi << 32) | (u64)lo;
  const int i = lane >> 2, g = lane & 3;
  const int t = row >> 5, rb = (row >> 4) & 1, r16 = row & 15;
  mnf[((size_t)(t * 2 + rb) * 16 + i) * 64 + (r16 | (g << 4))] = v;
}

// ---- kernel 2: fused x @ mn^T (fp8 MFMA) -> entropy partials ----
// 256 thr = 4 waves; wave owns 16 x-rows (raw-fp8 regs, logits scaled by
// 1/||x||) and covers all 32 clusters of each tile. 2x16KB LDS ring via
// global_load_lds; 1 barrier/tile. Inner phase: batch 16 ds_reads ->
// dependency-free MFMA cluster (2 acc chains), twice; setprio around MFMA.
__global__ __launch_bounds__(256, 4) void kmain(const float* __restrict__ x,
                                                const u64* __restrict__ mnf,
                                                float* __restrict__ acc_out) {
  __shared__ __align__(16) char mbuf[2][16384];
  const int tid = threadIdx.x, wave = tid >> 6, lane = tid & 63;
  const int r16 = lane & 15, g = lane >> 4;

  // stage tile t into buffer b: 16KB linear copy, 4x (256 thr x 16B)
  auto stage = [&](int t, int b) {
    const char* gp = (const char*)mnf + (size_t)t * 16384 + wave * 1024 + lane * 16;
    char* lp = &mbuf[b][wave * 1024];   // wave-uniform base; HW adds lane*16
#pragma unroll
    for (int q = 0; q < 4; ++q)
      gload_lds16(gp + q * 4096, lp + q * 4096);
  };

  stage(0, 0);    // issue early; x prologue hides the latency
  stage(1, 1);

  // ---- x prologue, single pass: pack RAW fp8 + accumulate sum-of-squares ----
  long xb[16];
  const int row0 = blockIdx.x * 64 + wave * 16;
  const float* px = x + (size_t)(row0 + r16) * N_F + g * 8;
  float ss = 0.f;
#pragma unroll
  for (int i = 0; i < 16; ++i) {
    float4 a = *(const float4*)(px + i * 32);
    float4 b = *(const float4*)(px + i * 32 + 4);
    ss += a.x*a.x + a.y*a.y + a.z*a.z + a.w*a.w
        + b.x*b.x + b.y*b.y + b.z*b.z + b.w*b.w;
    unsigned lo = pk8<false>(a.x, a.y, 0u);
    lo = pk8<true>(a.z, a.w, lo);
    unsigned hi = pk8<false>(b.x, b.y, 0u);
    hi = pk8<true>(b.z, b.w, hi);
    xb[i] = (long)(((u64)hi << 32) | lo);
  }
  ss += __shfl_xor(ss, 16); ss += __shfl_xor(ss, 32);
  const float inv = 1.0f / fmaxf(sqrtf(ss), 1e-12f);   // per-lane = x-row r16

  float L = 0.f, S = 0.f;

  asm volatile("s_waitcnt vmcnt(4)" ::: "memory");   // tile 0 staged
  __builtin_amdgcn_s_barrier();

#pragma unroll 1
  for (int t = 0; t < 32; ++t) {
    const int b = t & 1;
    if (t + 1 < 32) stage(t + 1, b ^ 1);   // buf^1's readers finished last iter

    const char* mb = &mbuf[b][lane * 8];
    f32x4 a0e = {0.f,0.f,0.f,0.f}, a0o = {0.f,0.f,0.f,0.f};
    f32x4 a1e = {0.f,0.f,0.f,0.f}, a1o = {0.f,0.f,0.f,0.f};

    // ---- half 0 (clusters 0-15): batch reads, then MFMA cluster ----
    long f[16];
#pragma unroll
    for (int i = 0; i < 16; ++i) f[i] = *(const long*)(mb + i * 512);
    __builtin_amdgcn_s_setprio(1);
#pragma unroll
    for (int i = 0; i < 8; ++i) {
      a0e = __builtin_amdgcn_mfma_f32_16x16x32_fp8_fp8(f[2*i],   xb[2*i],   a0e, 0, 0, 0);
      a0o = __builtin_amdgcn_mfma_f32_16x16x32_fp8_fp8(f[2*i+1], xb[2*i+1], a0o, 0, 0, 0);
    }
    __builtin_amdgcn_s_setprio(0);

    // ---- half 1 (clusters 16-31) ----
    long h[16];
#pragma unroll
    for (int i = 0; i < 16; ++i) h[i] = *(const long*)(mb + 8192 + i * 512);
    __builtin_amdgcn_s_setprio(1);
#pragma unroll
    for (int i = 0; i < 8; ++i) {
      a1e = __builtin_amdgcn_mfma_f32_16x16x32_fp8_fp8(h[2*i],   xb[2*i],   a1e, 0, 0, 0);
      a1o = __builtin_amdgcn_mfma_f32_16x16x32_fp8_fp8(h[2*i+1], xb[2*i+1], a1o, 0, 0, 0);
    }
    __builtin_amdgcn_s_setprio(0);

    // ---- entropy partials ----
#pragma unroll
    for (int r = 0; r < 4; ++r) {
      float y0 = (a0e[r] + a0o[r]) * inv;
      float e0 = __expf(y0); L += e0; S = fmaf(e0, y0, S);
      float y1 = (a1e[r] + a1o[r]) * inv;
      float e1 = __expf(y1); L += e1; S = fmaf(e1, y1, S);
    }
    asm volatile("s_waitcnt vmcnt(0)" ::: "memory");   // t+1 staged (issued a phase ago)
    __builtin_amdgcn_s_barrier();
  }

  // ---- finish: reduce the 4 g-groups (disjoint cluster subsets per row) ----
  L += __shfl_xor(L, 16); L += __shfl_xor(L, 32);
  S += __shfl_xor(S, 16); S += __shfl_xor(S, 32);
  // each row's (L,S) now replicated on 4 lanes -> weight 1/4, butterfly-sum
  float hh = 0.25f * (__logf(L) - S / L);
#pragma unroll
  for (int off = 1; off < 64; off <<= 1) hh += __shfl_xor(hh, off);
  if (lane == 0) atomicAdd(acc_out, hh);
}

// ---- kernel 3: finalize ----
__global__ void kfin(const float* __restrict__ acc, float* __restrict__ out) {
  const float mean = acc[0] * (1.0f / (float)N_ROWS);
  out[0] = mean;   // total
  out[1] = mean;   // intra
  out[2] = 0.0f;   // inter
}

extern "C" void kernel_launch(void* const* d_in, const int* in_sizes, int n_in,
                              void* d_out, int out_size, void* d_ws, size_t ws_size,
                              hipStream_t stream) {
  const float* x = (const float*)d_in[0];
  const float* m = (const float*)d_in[1];
  float* acc = (float*)d_ws;
  u64* mnf = (u64*)((char*)d_ws + 64);

  (void)hipMemsetAsync(d_ws, 0, 64, stream);
  knorm_m<<<256, 256, 0, stream>>>(m, mnf);
  kmain<<<1024, 256, 0, stream>>>(x, mnf, acc);
  kfin<<<1, 1, 0, stream>>>(acc, (float*)d_out);
}